// Round 10
// baseline (41.745 us; speedup 1.0000x reference)
//
#include <hip/hip_runtime.h>
#include <math.h>
#include <stdint.h>

#define BROWS 262144
#define KCLS  101
#define ROWB  404
#define BATCH_ROWS 64
#define BATCH_BYTES (BATCH_ROWS * ROWB)   // 25856
#define NBATCH (BROWS / BATCH_ROWS)       // 4096
#define BLOCKS 1024
#define BPB    (NBATCH / BLOCKS)          // 4 batches per block

typedef const __attribute__((address_space(1))) uint32_t* gptr_t;
typedef __attribute__((address_space(3))) uint32_t*       lptr_t;

// Stage one 64-row batch (25856 B, exact) into LDS: 25 x 16B-wide + 1 x 4B-wide.
__device__ __forceinline__ void stage_batch(const char* src, char* dst, int lane) {
#pragma unroll
    for (int k = 0; k < 25; ++k)
        __builtin_amdgcn_global_load_lds((gptr_t)(src + k * 1024 + lane * 16),
                                         (lptr_t)(dst + k * 1024), 16, 0, 0);
    __builtin_amdgcn_global_load_lds((gptr_t)(src + 25600 + lane * 4),
                                     (lptr_t)(dst + 25600), 4, 0, 0);
}

// Row-per-lane: lane l streams its entire row (101 elems) from LDS.
// All loss terms are lane-local accumulations; no shuffles, no pads, no masks
// beyond (t<=y). Single-wave blocks: no barriers; counted vmcnt keeps the
// next-batch prefetch in flight across the compute.
extern "C" __global__ void __launch_bounds__(64)
ord_main(const float* __restrict__ logit,
         const int*   __restrict__ labels,
         const float* __restrict__ cw,
         float*       __restrict__ partial)
{
    __shared__ __align__(16) char  smem[2 * BATCH_BYTES];   // 51712 B
    __shared__ __align__(16) int   ylds[256];               // 1024 B
    __shared__ __align__(16) float cwlds[128];              // 512 B

    const int lane  = threadIdx.x;            // 0..63
    const int gbase = blockIdx.x * BPB;

    // ---- prologue staging (all tracked by vmcnt) ----
    stage_batch((const char*)logit + (size_t)gbase * BATCH_BYTES, smem, lane);
    // labels for this block's 4 batches: 256 ints = 1024 B, one 16B-wide issue
    __builtin_amdgcn_global_load_lds((gptr_t)((const char*)(labels + gbase * 64) + lane * 16),
                                     (lptr_t)ylds, 16, 0, 0);
    // class weights: 404 B via two 4B-wide issues (second clamped; pad unread)
    {
        const char* cwb = (const char*)cw;
        int o1 = 256 + 4 * lane; o1 = (o1 > 400) ? 400 : o1;
        __builtin_amdgcn_global_load_lds((gptr_t)(cwb + 4 * lane), (lptr_t)cwlds, 4, 0, 0);
        __builtin_amdgcn_global_load_lds((gptr_t)(cwb + o1),
                                         (lptr_t)((char*)cwlds + 256), 4, 0, 0);
    }

    const float inv_logK = 1.0f / logf(101.0f);   // folds at compile time

    float tacc = 0.0f;

#pragma unroll
    for (int k = 0; k < BPB; ++k) {
        if (k + 1 < BPB) {
            stage_batch((const char*)logit + (size_t)(gbase + k + 1) * BATCH_BYTES,
                        smem + ((k + 1) & 1) * BATCH_BYTES, lane);
            asm volatile("s_waitcnt vmcnt(26)" ::: "memory");  // batch k ready; prefetch in flight
        } else {
            asm volatile("s_waitcnt vmcnt(0)" ::: "memory");
        }

        const float* lrow = (const float*)(smem + (k & 1) * BATCH_BYTES) + lane * KCLS;
        const int    y    = ylds[k * 64 + lane];
        const float  wy   = cwlds[y];

        // ---- streaming pass over 101 classes (fully unrolled, all t const) ----
        float A = 0.f, sP2 = 0.f, T = 0.f, Bm = 0.f, Cm = 0.f, uniS = 0.f, ep = 0.f;
#pragma unroll
        for (int t = 0; t < KCLS; ++t) {
            const float e = __expf(lrow[t]);              // no max-shift: |x| < ~6
            uniS = (t == 0) ? e : (uniS + __builtin_fabsf(ep - e));
            A += e;                                        // inclusive prefix P_t
            sP2 = __builtin_fmaf(A, A, sP2);               // sum P^2
            T  += (t <= y) ? A : 0.0f;                     // sum_{t<=y} P_t
            Bm  = __builtin_fmaf(e, (float)t, Bm);         // sum e*t
            Cm  = __builtin_fmaf(e, (float)(t * t), Cm);   // sum e*t^2
            ep  = e;
        }
        uniS += ep;                                        // right phantom p100

        // ---- epilogue (per lane, all lanes useful) ----
        const float S   = A;
        const float inv = __builtin_amdgcn_rcpf(S);
        const float lnS = __logf(S);
        const int   ym  = (y > 0)   ? y - 1 : 0;
        const int   yp  = (y < 100) ? y + 1 : 100;
        const float xy  = lrow[y];
        const float eY  = __expf(xy);
        const float eL  = (y > 0)   ? __expf(lrow[ym]) : 0.0f;
        const float eR  = (y < 100) ? __expf(lrow[yp]) : 0.0f;

        const float py   = eY * inv;
        const float tail = 1.0f - (eL + eY + eR) * inv;
        const float lp   = fmaxf(__builtin_fmaf(fmaxf(eL, eR), inv, 0.25f - py), 0.0f);
        const float yf   = (float)y;
        const float eseRaw = __builtin_fmaf(yf, __builtin_fmaf(yf, A, -2.0f * Bm), Cm);
        // emd = invK * (inv^2*sumP2 - 2*inv*T + (y+1))   [exact expansion]
        const float emd = (1.0f / 101.0f) *
            (__builtin_fmaf(inv * inv, sP2, (float)(y + 1)) - 2.0f * inv * T);

        const float rowv = wy * (lnS - xy) * inv_logK              // CE
                         + (wy * 1.0e-4f * inv) * eseRaw           // ESE
                         + emd                                     // EMD
                         + 2.5f * (tail + lp)                      // tail + local peak
                         + __builtin_fmaf(0.00375f * inv, uniS, -0.0075f * py); // uni
        tacc += rowv;
    }

    // ---- single-wave butterfly reduction (deterministic) ----
    tacc += __shfl_xor(tacc, 1);
    tacc += __shfl_xor(tacc, 2);
    tacc += __shfl_xor(tacc, 4);
    tacc += __shfl_xor(tacc, 8);
    tacc += __shfl_xor(tacc, 16);
    tacc += __shfl_xor(tacc, 32);

    if (lane == 0) partial[blockIdx.x] = tacc;
}

extern "C" __global__ void __launch_bounds__(256)
ord_final(const float* __restrict__ partial, float* __restrict__ out, int n)
{
    float v = 0.0f;
    for (int i = threadIdx.x; i < n; i += 256) v += partial[i];

    v += __shfl_xor(v, 1);
    v += __shfl_xor(v, 2);
    v += __shfl_xor(v, 4);
    v += __shfl_xor(v, 8);
    v += __shfl_xor(v, 16);
    v += __shfl_xor(v, 32);

    __shared__ float sb[4];
    const int lane = threadIdx.x & 63;
    const int wid  = threadIdx.x >> 6;
    if (lane == 0) sb[wid] = v;
    __syncthreads();
    if (threadIdx.x == 0)
        out[0] = ((sb[0] + sb[1]) + (sb[2] + sb[3])) * (1.0f / (float)BROWS);
}

extern "C" void kernel_launch(void* const* d_in, const int* in_sizes, int n_in,
                              void* d_out, int out_size, void* d_ws, size_t ws_size,
                              hipStream_t stream)
{
    const float* logit  = (const float*)d_in[0];
    const int*   labels = (const int*)d_in[1];
    const float* cw     = (const float*)d_in[2];
    float*       part   = (float*)d_ws;

    hipLaunchKernelGGL(ord_main, dim3(BLOCKS), dim3(64), 0, stream,
                       logit, labels, cw, part);
    hipLaunchKernelGGL(ord_final, dim3(1), dim3(256), 0, stream,
                       part, (float*)d_out, BLOCKS);
}

// Round 12
// 29.108 us; speedup vs baseline: 1.4341x; 1.4341x over previous
//
#include <hip/hip_runtime.h>
#include <math.h>
#include <stdint.h>

#define BROWS 262144
#define KCLS  101
#define ROWB  404
#define RPB   16                      // rows per batch (per wave)
#define BATCHB (RPB * ROWB)           // 6464 B
#define STAGEB 7168                   // 7 x 1KB staging issues (704 B pad)
#define NBPW  8                       // batches per wave
#define NWAVE (BROWS / (RPB * NBPW))  // 2048 single-wave blocks
#define TOTB  (BROWS * ROWB)          // 105,906,176 B

typedef const __attribute__((address_space(1))) uint32_t* gptr_t;
typedef __attribute__((address_space(3))) uint32_t*       lptr_t;

// Stage one 16-row batch (6464 B real, 7168 staged) into LDS.
// Per-lane src clamp handles the global tail (only the final batch overshoots).
__device__ __forceinline__ void stage_batch(const char* base, unsigned off,
                                            char* dst, int lane) {
#pragma unroll
    for (int k = 0; k < 7; ++k) {
        unsigned o = off + (unsigned)(k * 1024 + lane * 16);
        o = (o > (unsigned)(TOTB - 16)) ? (unsigned)(TOTB - 16) : o;
        __builtin_amdgcn_global_load_lds((gptr_t)(base + o),
                                         (lptr_t)(dst + k * 1024), 16, 0, 0);
    }
}

// 4 lanes per row: lane q owns classes [25q, 25q+n), n = 25,25,25,26.
// All terms are lane-local streams; prefix-offset algebra merges the 4 lanes:
//   sumP^2 = sp + 2E*w + n*E^2 ;  T = tl + m_q*E (m_q closed-form)
// Single-wave blocks (no barriers); counted vmcnt(7) keeps prefetch in flight.
extern "C" __global__ void __launch_bounds__(64)
ord_main(const float* __restrict__ logit,
         const int*   __restrict__ labels,
         const float* __restrict__ cw,
         float*       __restrict__ partial)
{
    __shared__ __align__(16) char  smem[2 * STAGEB];   // 14336 B
    __shared__ __align__(16) int   ylds[128];          // 128 labels (8 batches x 16)
    __shared__ __align__(16) float cwlds[128];         // 101 weights (+pad)

    const int lane = threadIdx.x;
    const int q    = lane & 3;
    const int g    = lane >> 2;                        // row within batch, 0..15
    const char* gb = (const char*)logit;
    const unsigned woff = (unsigned)blockIdx.x * (unsigned)(RPB * NBPW * ROWB);

    // ---- prologue staging (11 vmcnt-tracked issues) ----
    stage_batch(gb, woff, smem, lane);
    {
        const char* lb = (const char*)labels + (size_t)blockIdx.x * (RPB * NBPW * 4);
        __builtin_amdgcn_global_load_lds((gptr_t)(lb + lane * 4), (lptr_t)ylds, 4, 0, 0);
        __builtin_amdgcn_global_load_lds((gptr_t)(lb + 256 + lane * 4),
                                         (lptr_t)((char*)ylds + 256), 4, 0, 0);
        const char* cwb = (const char*)cw;
        unsigned o1 = 256u + (unsigned)(lane * 4); o1 = (o1 > 400u) ? 400u : o1;
        __builtin_amdgcn_global_load_lds((gptr_t)(cwb + lane * 4), (lptr_t)cwlds, 4, 0, 0);
        __builtin_amdgcn_global_load_lds((gptr_t)(cwb + o1),
                                         (lptr_t)((char*)cwlds + 256), 4, 0, 0);
    }

    const float inv_logK = 1.0f / logf(101.0f);        // folds at compile time
    const float invK     = 1.0f / 101.0f;
    const int   t0 = 25 * q;
    const int   nn = (q == 3) ? 26 : 25;
    const float nq = (float)nn;

    float tacc = 0.0f;

    for (int k = 0; k < NBPW; ++k) {
        if (k + 1 < NBPW) {
            stage_batch(gb, woff + (unsigned)((k + 1) * BATCHB),
                        smem + ((k + 1) & 1) * STAGEB, lane);
            asm volatile("s_waitcnt vmcnt(7)" ::: "memory");  // batch k ready; prefetch flying
        } else {
            asm volatile("s_waitcnt vmcnt(0)" ::: "memory");
        }

        const float* rowb = (const float*)(smem + (k & 1) * STAGEB) + g * KCLS;
        const float* lrow = rowb + t0;
        const int    y    = ylds[k * 16 + g];
        const float  wy   = cwlds[y];
        const float  yf   = (float)y;

        // ---- lane-local stream over 25 (+1 for q==3) classes ----
        float a = 0.f, w = 0.f, sp = 0.f, tl = 0.f, bm = 0.f, cm = 0.f;
        float us = 0.f, ef = 0.f, ep = 0.f;
#pragma unroll
        for (int i = 0; i < 25; ++i) {
            const int   t = t0 + i;
            const float e = __expf(lrow[i]);           // no max-shift: |x| < ~6
            if (i == 0) ef = e; else us += __builtin_fabsf(e - ep);
            a += e;                                    // local inclusive prefix L_i
            w += a;                                    // sum L_i
            sp = __builtin_fmaf(a, a, sp);             // sum L_i^2
            tl += (t <= y) ? a : 0.0f;                 // masked sum L_i
            bm = __builtin_fmaf(e, (float)t, bm);      // sum e*t   (global t)
            cm = __builtin_fmaf(e, (float)(t * t), cm);// sum e*t^2
            ep = e;
        }
        if (q == 3) {                                  // class 100
            const float e = __expf(lrow[25]);
            us += __builtin_fabsf(e - ep);
            a += e; w += a;
            sp = __builtin_fmaf(a, a, sp);
            tl += (y >= 100) ? a : 0.0f;
            bm = __builtin_fmaf(e, 100.0f, bm);
            cm = __builtin_fmaf(e, 10000.0f, cm);
            ep = e;
        }

        // ---- 4-lane merge ----
        float incl = a;
        { float u = __shfl_up(incl, 1, 4); incl += (q >= 1) ? u : 0.0f; }
        { float u = __shfl_up(incl, 2, 4); incl += (q >= 2) ? u : 0.0f; }
        const float S   = __shfl(incl, 3, 4);          // row total
        const float E   = incl - a;                    // exclusive e-prefix
        const float inv = __builtin_amdgcn_rcpf(S);
        const float nf  = __shfl_down(ef, 1, 4);       // next lane's first e (q==3 junk)

        int mi = y - t0 + 1; mi = (mi < 0) ? 0 : mi; mi = (mi > nn) ? nn : mi;
        const float spc  = __builtin_fmaf(nq * E, E, __builtin_fmaf(2.0f * E, w, sp));
        const float tlc  = __builtin_fmaf((float)mi, E, tl);
        const float eseC = __builtin_fmaf(yf, __builtin_fmaf(yf, a, -2.0f * bm), cm);
        const float uniC = us + ((q < 3) ? __builtin_fabsf(ep - nf) : 0.0f)
                         + ((q == 0) ? ef : 0.0f) + ((q == 3) ? ep : 0.0f);

        float part = (wy * 1.0e-4f * inv) * eseC;              // ESE
        part = __builtin_fmaf(invK * inv * inv, spc, part);    // EMD quad
        part = __builtin_fmaf(-2.0f * invK * inv, tlc, part);  // EMD cross
        part = __builtin_fmaf(0.00375f * inv, uniC, part);     // uni |delta|
        part += __shfl_xor(part, 1);
        part += __shfl_xor(part, 2);                           // group total

        // ---- epilogue (broadcast LDS reads; only q==0 accumulates) ----
        const int   ym = (y > 0)   ? y - 1 : 0;
        const int   yp = (y < 100) ? y + 1 : 100;
        const float xy = rowb[y];
        const float eY = __expf(xy);
        const float eL = (y > 0)   ? __expf(rowb[ym]) : 0.0f;
        const float eR = (y < 100) ? __expf(rowb[yp]) : 0.0f;
        const float lnS  = __logf(S);
        const float py   = eY * inv;
        const float tail = 1.0f - (eL + eY + eR) * inv;
        const float lp   = fmaxf(__builtin_fmaf(fmaxf(eL, eR), inv, 0.25f - py), 0.0f);
        const float extra = wy * (lnS - xy) * inv_logK         // CE
                          + 2.5f * (tail + lp)                 // tail + local peak
                          - 0.0075f * py                       // uni -2*cU*p_y
                          + invK * (float)(y + 1);             // EMD scalar remainder

        tacc += (q == 0) ? (part + extra) : 0.0f;
    }

    // ---- single-wave butterfly (deterministic) ----
    tacc += __shfl_xor(tacc, 1);
    tacc += __shfl_xor(tacc, 2);
    tacc += __shfl_xor(tacc, 4);
    tacc += __shfl_xor(tacc, 8);
    tacc += __shfl_xor(tacc, 16);
    tacc += __shfl_xor(tacc, 32);

    if (lane == 0) partial[blockIdx.x] = tacc;
}

extern "C" __global__ void __launch_bounds__(256)
ord_final(const float* __restrict__ partial, float* __restrict__ out, int n)
{
    float v = 0.0f;
    for (int i = threadIdx.x; i < n; i += 256) v += partial[i];

    v += __shfl_xor(v, 1);
    v += __shfl_xor(v, 2);
    v += __shfl_xor(v, 4);
    v += __shfl_xor(v, 8);
    v += __shfl_xor(v, 16);
    v += __shfl_xor(v, 32);

    __shared__ float sb[4];
    const int lane = threadIdx.x & 63;
    const int wid  = threadIdx.x >> 6;
    if (lane == 0) sb[wid] = v;
    __syncthreads();
    if (threadIdx.x == 0)
        out[0] = ((sb[0] + sb[1]) + (sb[2] + sb[3])) * (1.0f / (float)BROWS);
}

extern "C" void kernel_launch(void* const* d_in, const int* in_sizes, int n_in,
                              void* d_out, int out_size, void* d_ws, size_t ws_size,
                              hipStream_t stream)
{
    const float* logit  = (const float*)d_in[0];
    const int*   labels = (const int*)d_in[1];
    const float* cw     = (const float*)d_in[2];
    float*       part   = (float*)d_ws;

    hipLaunchKernelGGL(ord_main, dim3(NWAVE), dim3(64), 0, stream,
                       logit, labels, cw, part);
    hipLaunchKernelGGL(ord_final, dim3(1), dim3(256), 0, stream,
                       part, (float*)d_out, NWAVE);
}